// Round 1
// baseline (15631.456 us; speedup 1.0000x reference)
//
#include <hip/hip_runtime.h>
#include <math.h>

// ---------------------------------------------------------------------------
// 2-layer GCN forward (GCNConv normalize=True, add_self_loops=True)
//   deg[c]   = 1 + sum_{e: col[e]=c} w[e]
//   dinv     = rsqrt(deg)
//   norm[e]  = dinv[row]*w*dinv[col];  self-loop norm_i = dinv[i]^2
//   h1       = relu( scatter(norm * (x@W1)[row] -> col) + dinv^2*(x@W1) + b1 )
//   h2       = scatter(norm * (h1@W2)[row] -> col) + dinv^2*(h1@W2) + b2
//   out      = log_softmax(h2, axis=1)   (2 classes)
// ---------------------------------------------------------------------------

__global__ __launch_bounds__(256) void k_init_deg(float* deg, int n) {
    int i = blockIdx.x * blockDim.x + threadIdx.x;
    if (i < n) deg[i] = 1.0f;   // self-loop weight
}

__global__ __launch_bounds__(256) void k_deg_accum(const int* __restrict__ col,
                                                   const float* __restrict__ w,
                                                   float* __restrict__ deg, int E) {
    int i = blockIdx.x * blockDim.x + threadIdx.x;
    if (i < E) atomicAdd(&deg[col[i]], w[i]);
}

__global__ __launch_bounds__(256) void k_rsqrt(float* deg, int n) {
    int i = blockIdx.x * blockDim.x + threadIdx.x;
    if (i < n) {
        float d = deg[i];
        deg[i] = (d > 0.0f) ? rsqrtf(d) : 0.0f;
    }
}

// h1[i][0..15] = x[i][0..10] @ W1(11x16)
__global__ __launch_bounds__(256) void k_gemm1(const float* __restrict__ x,
                                               const float* __restrict__ W1,
                                               float* __restrict__ h1, int n) {
    __shared__ float sW[11 * 16];
    for (int t = threadIdx.x; t < 11 * 16; t += blockDim.x) sW[t] = W1[t];
    __syncthreads();
    int i = blockIdx.x * blockDim.x + threadIdx.x;
    if (i >= n) return;
    float xi[11];
#pragma unroll
    for (int k = 0; k < 11; k++) xi[k] = x[(size_t)i * 11 + k];
#pragma unroll
    for (int f = 0; f < 16; f++) {
        float acc = 0.0f;
#pragma unroll
        for (int k = 0; k < 11; k++) acc += xi[k] * sW[k * 16 + f];
        h1[(size_t)i * 16 + f] = acc;
    }
}

// acc1[col] += dinv[row]*w*dinv[col] * h1[row]   (16 features)
__global__ __launch_bounds__(256) void k_scatter16(const int* __restrict__ row,
                                                   const int* __restrict__ col,
                                                   const float* __restrict__ w,
                                                   const float* __restrict__ dinv,
                                                   const float* __restrict__ h1,
                                                   float* __restrict__ acc, int E) {
    int i = blockIdx.x * blockDim.x + threadIdx.x;
    if (i >= E) return;
    int r = row[i], c = col[i];
    float nw = dinv[r] * w[i] * dinv[c];
    const float4* hr = (const float4*)(h1 + (size_t)r * 16);
    float* out = acc + (size_t)c * 16;
#pragma unroll
    for (int q = 0; q < 4; q++) {
        float4 hv = hr[q];
        atomicAdd(out + q * 4 + 0, nw * hv.x);
        atomicAdd(out + q * 4 + 1, nw * hv.y);
        atomicAdd(out + q * 4 + 2, nw * hv.z);
        atomicAdd(out + q * 4 + 3, nw * hv.w);
    }
}

// acc1 += dinv^2 * h1 + b1 ; relu (in place)
__global__ __launch_bounds__(256) void k_post1(const float* __restrict__ h1,
                                               const float* __restrict__ dinv,
                                               const float* __restrict__ b1,
                                               float* __restrict__ acc, int n) {
    int i = blockIdx.x * blockDim.x + threadIdx.x;
    if (i >= n) return;
    float dv = dinv[i];
    float cs = dv * dv;
#pragma unroll
    for (int f = 0; f < 16; f++) {
        float v = acc[(size_t)i * 16 + f] + cs * h1[(size_t)i * 16 + f] + b1[f];
        acc[(size_t)i * 16 + f] = v > 0.0f ? v : 0.0f;
    }
}

// h2[i][0..1] = hrelu[i][0..15] @ W2(16x2)
__global__ __launch_bounds__(256) void k_gemm2(const float* __restrict__ hrelu,
                                               const float* __restrict__ W2,
                                               float* __restrict__ h2, int n) {
    __shared__ float sW[32];
    for (int t = threadIdx.x; t < 32; t += blockDim.x) sW[t] = W2[t];
    __syncthreads();
    int i = blockIdx.x * blockDim.x + threadIdx.x;
    if (i >= n) return;
    float a0 = 0.0f, a1 = 0.0f;
#pragma unroll
    for (int f = 0; f < 16; f++) {
        float h = hrelu[(size_t)i * 16 + f];
        a0 += h * sW[f * 2 + 0];
        a1 += h * sW[f * 2 + 1];
    }
    h2[(size_t)i * 2 + 0] = a0;
    h2[(size_t)i * 2 + 1] = a1;
}

// out[col] += dinv[row]*w*dinv[col] * h2[row]   (2 features)
__global__ __launch_bounds__(256) void k_scatter2(const int* __restrict__ row,
                                                  const int* __restrict__ col,
                                                  const float* __restrict__ w,
                                                  const float* __restrict__ dinv,
                                                  const float* __restrict__ h2,
                                                  float* __restrict__ out, int E) {
    int i = blockIdx.x * blockDim.x + threadIdx.x;
    if (i >= E) return;
    int r = row[i], c = col[i];
    float nw = dinv[r] * w[i] * dinv[c];
    atomicAdd(&out[(size_t)c * 2 + 0], nw * h2[(size_t)r * 2 + 0]);
    atomicAdd(&out[(size_t)c * 2 + 1], nw * h2[(size_t)r * 2 + 1]);
}

// out += dinv^2*h2 + b2 ; log_softmax over 2 classes (in place)
__global__ __launch_bounds__(256) void k_final(const float* __restrict__ h2,
                                               const float* __restrict__ dinv,
                                               const float* __restrict__ b2,
                                               float* __restrict__ out, int n) {
    int i = blockIdx.x * blockDim.x + threadIdx.x;
    if (i >= n) return;
    float dv = dinv[i];
    float cs = dv * dv;
    float v0 = out[(size_t)i * 2 + 0] + cs * h2[(size_t)i * 2 + 0] + b2[0];
    float v1 = out[(size_t)i * 2 + 1] + cs * h2[(size_t)i * 2 + 1] + b2[1];
    float m = fmaxf(v0, v1);
    float lse = m + logf(expf(v0 - m) + expf(v1 - m));
    out[(size_t)i * 2 + 0] = v0 - lse;
    out[(size_t)i * 2 + 1] = v1 - lse;
}

extern "C" void kernel_launch(void* const* d_in, const int* in_sizes, int n_in,
                              void* d_out, int out_size, void* d_ws, size_t ws_size,
                              hipStream_t stream) {
    const float* x  = (const float*)d_in[0];
    const int*   ei = (const int*)d_in[1];
    const float* ew = (const float*)d_in[2];
    const float* W1 = (const float*)d_in[3];
    const float* b1 = (const float*)d_in[4];
    const float* W2 = (const float*)d_in[5];
    const float* b2 = (const float*)d_in[6];

    const int n = in_sizes[0] / 11;
    const int E = in_sizes[2];
    const int* rowp = ei;       // sources
    const int* colp = ei + E;   // targets

    float* ws   = (float*)d_ws;
    float* dinv = ws;                       // n floats (deg -> dinv in place)
    float* h1   = ws + (size_t)n;           // 16n floats (reused as h2: 2n)
    float* acc1 = ws + (size_t)n * 17;      // 16n floats (becomes h_relu)
    float* outf = (float*)d_out;            // 2n floats

    const int TB = 256;
    const int gN  = (n + TB - 1) / TB;
    const int gE  = (E + TB - 1) / TB;

    // norm
    k_init_deg<<<gN, TB, 0, stream>>>(dinv, n);
    k_deg_accum<<<gE, TB, 0, stream>>>(colp, ew, dinv, E);
    k_rsqrt<<<gN, TB, 0, stream>>>(dinv, n);

    // layer 1
    k_gemm1<<<gN, TB, 0, stream>>>(x, W1, h1, n);
    hipMemsetAsync(acc1, 0, (size_t)n * 16 * sizeof(float), stream);
    k_scatter16<<<gE, TB, 0, stream>>>(rowp, colp, ew, dinv, h1, acc1, E);
    k_post1<<<gN, TB, 0, stream>>>(h1, dinv, b1, acc1, n);   // acc1 -> h_relu

    // layer 2 (h2 reuses h1 buffer)
    float* h2 = h1;
    k_gemm2<<<gN, TB, 0, stream>>>(acc1, W2, h2, n);
    hipMemsetAsync(outf, 0, (size_t)n * 2 * sizeof(float), stream);
    k_scatter2<<<gE, TB, 0, stream>>>(rowp, colp, ew, dinv, h2, outf, E);
    k_final<<<gN, TB, 0, stream>>>(h2, dinv, b2, outf, n);
}

// Round 2
// 4277.774 us; speedup vs baseline: 3.6541x; 3.6541x over previous
//
#include <hip/hip_runtime.h>
#include <math.h>

// ---------------------------------------------------------------------------
// 2-layer GCN forward. Strategy: build CSR (target-sorted edge list) once per
// call, then PULL-gather both conv layers (zero float atomics in hot path).
//   deg[c]  = 1 + sum w[e];  dinv = rsqrt(deg);  norm[e] = dinv[r]*w*dinv[c]
//   hrelu   = relu( pull(norm*h1) + dinv^2*h1 + b1 ),  h1 = x@W1
//   out     = log_softmax( pull(norm*h2) + dinv^2*h2 + b2 ),  h2 = hrelu@W2
// Fallback to the atomic-scatter path if ws_size is too small.
// ---------------------------------------------------------------------------

// ---------------- common small kernels ----------------

__global__ __launch_bounds__(256) void k_init_deg(float* deg, int n) {
    int i = blockIdx.x * blockDim.x + threadIdx.x;
    if (i < n) deg[i] = 1.0f;   // self-loop weight
}

__global__ __launch_bounds__(256) void k_rsqrt(float* deg, int n) {
    int i = blockIdx.x * blockDim.x + threadIdx.x;
    if (i < n) {
        float d = deg[i];
        deg[i] = (d > 0.0f) ? rsqrtf(d) : 0.0f;
    }
}

// h1[i][0..15] = x[i][0..10] @ W1(11x16)
__global__ __launch_bounds__(256) void k_gemm1(const float* __restrict__ x,
                                               const float* __restrict__ W1,
                                               float* __restrict__ h1, int n) {
    __shared__ float sW[11 * 16];
    for (int t = threadIdx.x; t < 11 * 16; t += blockDim.x) sW[t] = W1[t];
    __syncthreads();
    int i = blockIdx.x * blockDim.x + threadIdx.x;
    if (i >= n) return;
    float xi[11];
#pragma unroll
    for (int k = 0; k < 11; k++) xi[k] = x[(size_t)i * 11 + k];
#pragma unroll
    for (int f = 0; f < 16; f++) {
        float acc = 0.0f;
#pragma unroll
        for (int k = 0; k < 11; k++) acc += xi[k] * sW[k * 16 + f];
        h1[(size_t)i * 16 + f] = acc;
    }
}

// h2[i][0..1] = hrelu[i][0..15] @ W2(16x2)
__global__ __launch_bounds__(256) void k_gemm2(const float* __restrict__ hrelu,
                                               const float* __restrict__ W2,
                                               float* __restrict__ h2, int n) {
    __shared__ float sW[32];
    for (int t = threadIdx.x; t < 32; t += blockDim.x) sW[t] = W2[t];
    __syncthreads();
    int i = blockIdx.x * blockDim.x + threadIdx.x;
    if (i >= n) return;
    float a0 = 0.0f, a1 = 0.0f;
#pragma unroll
    for (int f = 0; f < 16; f++) {
        float h = hrelu[(size_t)i * 16 + f];
        a0 += h * sW[f * 2 + 0];
        a1 += h * sW[f * 2 + 1];
    }
    h2[(size_t)i * 2 + 0] = a0;
    h2[(size_t)i * 2 + 1] = a1;
}

// ---------------- CSR build ----------------

// cnt[c]++ (int) and deg[c]+=w (float) per edge
__global__ __launch_bounds__(256) void k_hist(const int* __restrict__ col,
                                              const float* __restrict__ w,
                                              int* __restrict__ cnt,
                                              float* __restrict__ deg, int E) {
    int i = blockIdx.x * blockDim.x + threadIdx.x;
    if (i >= E) return;
    int c = col[i];
    atomicAdd(&cnt[c], 1);
    atomicAdd(&deg[c], w[i]);
}

// block-local exclusive scan (256/block); block totals to bsum
__global__ __launch_bounds__(256) void k_scan_local(const int* __restrict__ cnt,
                                                    int* __restrict__ out,
                                                    int* __restrict__ bsum, int n) {
    __shared__ int s[256];
    int t = threadIdx.x;
    int i = blockIdx.x * 256 + t;
    int v = (i < n) ? cnt[i] : 0;
    s[t] = v;
    __syncthreads();
    for (int off = 1; off < 256; off <<= 1) {
        int u = (t >= off) ? s[t - off] : 0;
        __syncthreads();
        s[t] += u;
        __syncthreads();
    }
    if (i < n) out[i] = s[t] - v;          // exclusive
    if (t == 255) bsum[blockIdx.x] = s[255];
}

// single-block exclusive scan of block sums (with carry across chunks)
__global__ __launch_bounds__(256) void k_scan_sums(int* __restrict__ bsum, int nb) {
    __shared__ int s[256];
    __shared__ int carry;
    int t = threadIdx.x;
    if (t == 0) carry = 0;
    __syncthreads();
    int chunks = (nb + 255) / 256;
    for (int ch = 0; ch < chunks; ch++) {
        int i = ch * 256 + t;
        int v = (i < nb) ? bsum[i] : 0;
        s[t] = v;
        __syncthreads();
        for (int off = 1; off < 256; off <<= 1) {
            int u = (t >= off) ? s[t - off] : 0;
            __syncthreads();
            s[t] += u;
            __syncthreads();
        }
        int incl = s[t];
        int my_carry = carry;
        if (i < nb) bsum[i] = incl - v + my_carry;
        __syncthreads();
        if (t == 0) carry = my_carry + s[255];
        __syncthreads();
    }
}

// offsets[i] = local[i] + bsum[block]; also write cursor copy; offsets[n] = E
__global__ __launch_bounds__(256) void k_scan_add(int* __restrict__ off,
                                                  const int* __restrict__ bsum,
                                                  int* __restrict__ cursor,
                                                  int n, int E) {
    int t = threadIdx.x;
    int i = blockIdx.x * 256 + t;
    if (i < n) {
        int v = off[i] + bsum[blockIdx.x];
        off[i] = v;
        cursor[i] = v;
    }
    if (i == 0) off[n] = E;
}

// scatter edges into target-sorted order, precompute norm
__global__ __launch_bounds__(256) void k_reorder(const int* __restrict__ row,
                                                 const int* __restrict__ col,
                                                 const float* __restrict__ w,
                                                 const float* __restrict__ dinv,
                                                 int* __restrict__ cursor,
                                                 int* __restrict__ rows_s,
                                                 float* __restrict__ norm_s, int E) {
    int i = blockIdx.x * blockDim.x + threadIdx.x;
    if (i >= E) return;
    int r = row[i], c = col[i];
    int pos = atomicAdd(&cursor[c], 1);
    rows_s[pos] = r;
    norm_s[pos] = dinv[r] * w[i] * dinv[c];
}

// ---------------- pull (gather) layers ----------------

// hrelu[i] = relu( sum_e norm*h1[rows_s[e]] + dinv[i]^2*h1[i] + b1 )
__global__ __launch_bounds__(256) void k_pull16(const int* __restrict__ off,
                                                const int* __restrict__ rows_s,
                                                const float* __restrict__ norm_s,
                                                const float* __restrict__ h1,
                                                const float* __restrict__ dinv,
                                                const float* __restrict__ b1,
                                                float* __restrict__ hrelu, int n) {
    int i = blockIdx.x * blockDim.x + threadIdx.x;
    if (i >= n) return;
    int s = off[i], e = off[i + 1];
    float dv = dinv[i];
    float cs = dv * dv;
    const float4* hi = (const float4*)(h1 + (size_t)i * 16);
    const float4* bb = (const float4*)b1;
    float4 a0, a1, a2, a3;
    {
        float4 h0 = hi[0], h1v = hi[1], h2v = hi[2], h3v = hi[3];
        float4 c0 = bb[0], c1 = bb[1], c2 = bb[2], c3 = bb[3];
        a0 = make_float4(cs * h0.x + c0.x, cs * h0.y + c0.y, cs * h0.z + c0.z, cs * h0.w + c0.w);
        a1 = make_float4(cs * h1v.x + c1.x, cs * h1v.y + c1.y, cs * h1v.z + c1.z, cs * h1v.w + c1.w);
        a2 = make_float4(cs * h2v.x + c2.x, cs * h2v.y + c2.y, cs * h2v.z + c2.z, cs * h2v.w + c2.w);
        a3 = make_float4(cs * h3v.x + c3.x, cs * h3v.y + c3.y, cs * h3v.z + c3.z, cs * h3v.w + c3.w);
    }
    for (int j = s; j < e; j++) {
        int r = rows_s[j];
        float nw = norm_s[j];
        const float4* hr = (const float4*)(h1 + (size_t)r * 16);
        float4 h0 = hr[0], h1v = hr[1], h2v = hr[2], h3v = hr[3];
        a0.x += nw * h0.x;  a0.y += nw * h0.y;  a0.z += nw * h0.z;  a0.w += nw * h0.w;
        a1.x += nw * h1v.x; a1.y += nw * h1v.y; a1.z += nw * h1v.z; a1.w += nw * h1v.w;
        a2.x += nw * h2v.x; a2.y += nw * h2v.y; a2.z += nw * h2v.z; a2.w += nw * h2v.w;
        a3.x += nw * h3v.x; a3.y += nw * h3v.y; a3.z += nw * h3v.z; a3.w += nw * h3v.w;
    }
    float4* o = (float4*)(hrelu + (size_t)i * 16);
    a0.x = fmaxf(a0.x, 0.f); a0.y = fmaxf(a0.y, 0.f); a0.z = fmaxf(a0.z, 0.f); a0.w = fmaxf(a0.w, 0.f);
    a1.x = fmaxf(a1.x, 0.f); a1.y = fmaxf(a1.y, 0.f); a1.z = fmaxf(a1.z, 0.f); a1.w = fmaxf(a1.w, 0.f);
    a2.x = fmaxf(a2.x, 0.f); a2.y = fmaxf(a2.y, 0.f); a2.z = fmaxf(a2.z, 0.f); a2.w = fmaxf(a2.w, 0.f);
    a3.x = fmaxf(a3.x, 0.f); a3.y = fmaxf(a3.y, 0.f); a3.z = fmaxf(a3.z, 0.f); a3.w = fmaxf(a3.w, 0.f);
    o[0] = a0; o[1] = a1; o[2] = a2; o[3] = a3;
}

// out[i] = log_softmax( sum_e norm*h2[rows_s[e]] + dinv^2*h2[i] + b2 )
__global__ __launch_bounds__(256) void k_pull2(const int* __restrict__ off,
                                               const int* __restrict__ rows_s,
                                               const float* __restrict__ norm_s,
                                               const float* __restrict__ h2,
                                               const float* __restrict__ dinv,
                                               const float* __restrict__ b2,
                                               float* __restrict__ out, int n) {
    int i = blockIdx.x * blockDim.x + threadIdx.x;
    if (i >= n) return;
    int s = off[i], e = off[i + 1];
    float dv = dinv[i];
    float cs = dv * dv;
    float v0 = cs * h2[(size_t)i * 2 + 0] + b2[0];
    float v1 = cs * h2[(size_t)i * 2 + 1] + b2[1];
    for (int j = s; j < e; j++) {
        int r = rows_s[j];
        float nw = norm_s[j];
        float2 hv = *(const float2*)(h2 + (size_t)r * 2);
        v0 += nw * hv.x;
        v1 += nw * hv.y;
    }
    float m = fmaxf(v0, v1);
    float lse = m + logf(expf(v0 - m) + expf(v1 - m));
    out[(size_t)i * 2 + 0] = v0 - lse;
    out[(size_t)i * 2 + 1] = v1 - lse;
}

// ---------------- fallback atomic-scatter kernels (proven path) ----------------

__global__ __launch_bounds__(256) void k_deg_accum(const int* __restrict__ col,
                                                   const float* __restrict__ w,
                                                   float* __restrict__ deg, int E) {
    int i = blockIdx.x * blockDim.x + threadIdx.x;
    if (i < E) atomicAdd(&deg[col[i]], w[i]);
}

__global__ __launch_bounds__(256) void k_scatter16(const int* __restrict__ row,
                                                   const int* __restrict__ col,
                                                   const float* __restrict__ w,
                                                   const float* __restrict__ dinv,
                                                   const float* __restrict__ h1,
                                                   float* __restrict__ acc, int E) {
    int i = blockIdx.x * blockDim.x + threadIdx.x;
    if (i >= E) return;
    int r = row[i], c = col[i];
    float nw = dinv[r] * w[i] * dinv[c];
    const float4* hr = (const float4*)(h1 + (size_t)r * 16);
    float* o = acc + (size_t)c * 16;
#pragma unroll
    for (int q = 0; q < 4; q++) {
        float4 hv = hr[q];
        atomicAdd(o + q * 4 + 0, nw * hv.x);
        atomicAdd(o + q * 4 + 1, nw * hv.y);
        atomicAdd(o + q * 4 + 2, nw * hv.z);
        atomicAdd(o + q * 4 + 3, nw * hv.w);
    }
}

__global__ __launch_bounds__(256) void k_post1(const float* __restrict__ h1,
                                               const float* __restrict__ dinv,
                                               const float* __restrict__ b1,
                                               float* __restrict__ acc, int n) {
    int i = blockIdx.x * blockDim.x + threadIdx.x;
    if (i >= n) return;
    float dv = dinv[i];
    float cs = dv * dv;
#pragma unroll
    for (int f = 0; f < 16; f++) {
        float v = acc[(size_t)i * 16 + f] + cs * h1[(size_t)i * 16 + f] + b1[f];
        acc[(size_t)i * 16 + f] = v > 0.0f ? v : 0.0f;
    }
}

__global__ __launch_bounds__(256) void k_scatter2(const int* __restrict__ row,
                                                  const int* __restrict__ col,
                                                  const float* __restrict__ w,
                                                  const float* __restrict__ dinv,
                                                  const float* __restrict__ h2,
                                                  float* __restrict__ out, int E) {
    int i = blockIdx.x * blockDim.x + threadIdx.x;
    if (i >= E) return;
    int r = row[i], c = col[i];
    float nw = dinv[r] * w[i] * dinv[c];
    atomicAdd(&out[(size_t)c * 2 + 0], nw * h2[(size_t)r * 2 + 0]);
    atomicAdd(&out[(size_t)c * 2 + 1], nw * h2[(size_t)r * 2 + 1]);
}

__global__ __launch_bounds__(256) void k_final(const float* __restrict__ h2,
                                               const float* __restrict__ dinv,
                                               const float* __restrict__ b2,
                                               float* __restrict__ out, int n) {
    int i = blockIdx.x * blockDim.x + threadIdx.x;
    if (i >= n) return;
    float dv = dinv[i];
    float cs = dv * dv;
    float v0 = out[(size_t)i * 2 + 0] + cs * h2[(size_t)i * 2 + 0] + b2[0];
    float v1 = out[(size_t)i * 2 + 1] + cs * h2[(size_t)i * 2 + 1] + b2[1];
    float m = fmaxf(v0, v1);
    float lse = m + logf(expf(v0 - m) + expf(v1 - m));
    out[(size_t)i * 2 + 0] = v0 - lse;
    out[(size_t)i * 2 + 1] = v1 - lse;
}

// ---------------- launch ----------------

static inline size_t align64(size_t x) { return (x + 63) & ~(size_t)63; }

extern "C" void kernel_launch(void* const* d_in, const int* in_sizes, int n_in,
                              void* d_out, int out_size, void* d_ws, size_t ws_size,
                              hipStream_t stream) {
    const float* x  = (const float*)d_in[0];
    const int*   ei = (const int*)d_in[1];
    const float* ew = (const float*)d_in[2];
    const float* W1 = (const float*)d_in[3];
    const float* b1 = (const float*)d_in[4];
    const float* W2 = (const float*)d_in[5];
    const float* b2 = (const float*)d_in[6];

    const int n = in_sizes[0] / 11;
    const int E = in_sizes[2];
    const int* rowp = ei;       // sources
    const int* colp = ei + E;   // targets

    const int TB = 256;
    const int gN = (n + TB - 1) / TB;
    const int gE = (E + TB - 1) / TB;
    const int nb = (n + 255) / 256;   // scan blocks

    // --- CSR-path workspace layout ---
    char* base = (char*)d_ws;
    size_t o_dinv  = 0;
    size_t o_cnt   = align64(o_dinv + (size_t)n * 4);         // int n (reused as cursor)
    size_t o_off   = align64(o_cnt + (size_t)n * 4);          // int n+1
    size_t o_bsum  = align64(o_off + (size_t)(n + 1) * 4);    // int nb
    size_t o_rows  = align64(o_bsum + (size_t)nb * 4);        // int E
    size_t o_norm  = align64(o_rows + (size_t)E * 4);         // float E
    size_t o_h1    = align64(o_norm + (size_t)E * 4);         // float 16n
    size_t o_hrelu = align64(o_h1 + (size_t)n * 16 * 4);      // float 16n
    size_t o_h2    = align64(o_hrelu + (size_t)n * 16 * 4);   // float 2n
    size_t needed  = align64(o_h2 + (size_t)n * 2 * 4);

    float* outf = (float*)d_out;

    if (ws_size >= needed) {
        float* dinv   = (float*)(base + o_dinv);
        int*   cnt    = (int*)(base + o_cnt);     // becomes cursor after scan
        int*   off    = (int*)(base + o_off);
        int*   bsum   = (int*)(base + o_bsum);
        int*   rows_s = (int*)(base + o_rows);
        float* norm_s = (float*)(base + o_norm);
        float* h1     = (float*)(base + o_h1);
        float* hrelu  = (float*)(base + o_hrelu);
        float* h2     = (float*)(base + o_h2);

        // norm + CSR build
        hipMemsetAsync(cnt, 0, (size_t)n * 4, stream);
        k_init_deg<<<gN, TB, 0, stream>>>(dinv, n);
        k_hist<<<gE, TB, 0, stream>>>(colp, ew, cnt, dinv, E);
        k_rsqrt<<<gN, TB, 0, stream>>>(dinv, n);
        k_scan_local<<<nb, 256, 0, stream>>>(cnt, off, bsum, n);
        k_scan_sums<<<1, 256, 0, stream>>>(bsum, nb);
        k_scan_add<<<nb, 256, 0, stream>>>(off, bsum, cnt, n, E);
        k_reorder<<<gE, TB, 0, stream>>>(rowp, colp, ew, dinv, cnt, rows_s, norm_s, E);

        // layer 1 (pull)
        k_gemm1<<<gN, TB, 0, stream>>>(x, W1, h1, n);
        k_pull16<<<gN, TB, 0, stream>>>(off, rows_s, norm_s, h1, dinv, b1, hrelu, n);

        // layer 2 (pull, fused log_softmax)
        k_gemm2<<<gN, TB, 0, stream>>>(hrelu, W2, h2, n);
        k_pull2<<<gN, TB, 0, stream>>>(off, rows_s, norm_s, h2, dinv, b2, outf, n);
    } else {
        // fallback: atomic-scatter path (proven correct in R1)
        float* ws   = (float*)d_ws;
        float* dinv = ws;
        float* h1   = ws + (size_t)n;
        float* acc1 = ws + (size_t)n * 17;

        k_init_deg<<<gN, TB, 0, stream>>>(dinv, n);
        k_deg_accum<<<gE, TB, 0, stream>>>(colp, ew, dinv, E);
        k_rsqrt<<<gN, TB, 0, stream>>>(dinv, n);

        k_gemm1<<<gN, TB, 0, stream>>>(x, W1, h1, n);
        hipMemsetAsync(acc1, 0, (size_t)n * 16 * sizeof(float), stream);
        k_scatter16<<<gE, TB, 0, stream>>>(rowp, colp, ew, dinv, h1, acc1, E);
        k_post1<<<gN, TB, 0, stream>>>(h1, dinv, b1, acc1, n);

        float* h2 = h1;
        k_gemm2<<<gN, TB, 0, stream>>>(acc1, W2, h2, n);
        hipMemsetAsync(outf, 0, (size_t)n * 2 * sizeof(float), stream);
        k_scatter2<<<gE, TB, 0, stream>>>(rowp, colp, ew, dinv, h2, outf, E);
        k_final<<<gN, TB, 0, stream>>>(h2, dinv, b2, outf, n);
    }
}

// Round 3
// 2518.657 us; speedup vs baseline: 6.2063x; 1.6984x over previous
//
#include <hip/hip_runtime.h>
#include <math.h>

// ---------------------------------------------------------------------------
// 2-layer GCN forward, CSR-pull strategy, minimal atomics:
//   k_hist_pack : ONE u64 atomic per edge -> (cnt<<32 | fixp(w)), rank = ret>>32
//   k_unpack    : dinv = rsqrt(1 + fixp^-1(low32))
//   scan(cnt)   : CSR offsets
//   k_reorder   : NO atomics; edge_s[off[c]+rank[i]] = {row, norm} (8B store)
//   k_pull16    : gather-accumulate layer1 + ReLU + fused @W2 -> h2 (8B/node)
//   k_pull2     : gather-accumulate layer2 + log_softmax -> out
// Fallback to R1 atomic-scatter path if workspace is too small.
// ---------------------------------------------------------------------------

#define FIXP_SCALE 8388608.0f          // 2^23
#define FIXP_INV   (1.0f / 8388608.0f)

typedef unsigned long long u64;

// ---------------- CSR build ----------------

__global__ __launch_bounds__(256) void k_hist_pack(const int* __restrict__ col,
                                                   const float* __restrict__ w,
                                                   u64* __restrict__ packed,
                                                   unsigned short* __restrict__ rank,
                                                   int E) {
    int i = blockIdx.x * blockDim.x + threadIdx.x;
    if (i >= E) return;
    int c = col[i];
    u64 add = ((u64)1 << 32) | (u64)(unsigned int)(w[i] * FIXP_SCALE + 0.5f);
    u64 old = atomicAdd(&packed[c], add);
    rank[i] = (unsigned short)(old >> 32);
}

__global__ __launch_bounds__(256) void k_unpack(const u64* __restrict__ packed,
                                                float* __restrict__ dinv, int n) {
    int i = blockIdx.x * blockDim.x + threadIdx.x;
    if (i >= n) return;
    float deg = 1.0f + (float)(unsigned int)(packed[i] & 0xffffffffu) * FIXP_INV;
    dinv[i] = rsqrtf(deg);   // deg >= 1 always (self-loop)
}

// block-local exclusive scan of cnt (= packed>>32); block totals to bsum
__global__ __launch_bounds__(256) void k_scan_local(const u64* __restrict__ packed,
                                                    int* __restrict__ out,
                                                    int* __restrict__ bsum, int n) {
    __shared__ int s[256];
    int t = threadIdx.x;
    int i = blockIdx.x * 256 + t;
    int v = (i < n) ? (int)(packed[i] >> 32) : 0;
    s[t] = v;
    __syncthreads();
    for (int off = 1; off < 256; off <<= 1) {
        int u = (t >= off) ? s[t - off] : 0;
        __syncthreads();
        s[t] += u;
        __syncthreads();
    }
    if (i < n) out[i] = s[t] - v;          // exclusive
    if (t == 255) bsum[blockIdx.x] = s[255];
}

__global__ __launch_bounds__(256) void k_scan_sums(int* __restrict__ bsum, int nb) {
    __shared__ int s[256];
    __shared__ int carry;
    int t = threadIdx.x;
    if (t == 0) carry = 0;
    __syncthreads();
    int chunks = (nb + 255) / 256;
    for (int ch = 0; ch < chunks; ch++) {
        int i = ch * 256 + t;
        int v = (i < nb) ? bsum[i] : 0;
        s[t] = v;
        __syncthreads();
        for (int off = 1; off < 256; off <<= 1) {
            int u = (t >= off) ? s[t - off] : 0;
            __syncthreads();
            s[t] += u;
            __syncthreads();
        }
        int incl = s[t];
        int my_carry = carry;
        if (i < nb) bsum[i] = incl - v + my_carry;
        __syncthreads();
        if (t == 0) carry = my_carry + s[255];
        __syncthreads();
    }
}

__global__ __launch_bounds__(256) void k_scan_add(int* __restrict__ off,
                                                  const int* __restrict__ bsum,
                                                  int n, int E) {
    int t = threadIdx.x;
    int i = blockIdx.x * 256 + t;
    if (i < n) off[i] += bsum[blockIdx.x];
    if (i == 0) off[n] = E;
}

// no atomics: pos = off[c] + rank[i]; one packed 8B scattered store per edge
__global__ __launch_bounds__(256) void k_reorder(const int* __restrict__ row,
                                                 const int* __restrict__ col,
                                                 const float* __restrict__ w,
                                                 const float* __restrict__ dinv,
                                                 const int* __restrict__ off,
                                                 const unsigned short* __restrict__ rank,
                                                 int2* __restrict__ edge_s, int E) {
    int i = blockIdx.x * blockDim.x + threadIdx.x;
    if (i >= E) return;
    int r = row[i], c = col[i];
    float nw = dinv[r] * w[i] * dinv[c];
    int pos = off[c] + (int)rank[i];
    int2 v;
    v.x = r;
    v.y = __float_as_int(nw);
    edge_s[pos] = v;
}

// ---------------- dense layers ----------------

// h1[i][0..15] = x[i][0..10] @ W1(11x16)
__global__ __launch_bounds__(256) void k_gemm1(const float* __restrict__ x,
                                               const float* __restrict__ W1,
                                               float* __restrict__ h1, int n) {
    __shared__ float sW[11 * 16];
    for (int t = threadIdx.x; t < 11 * 16; t += blockDim.x) sW[t] = W1[t];
    __syncthreads();
    int i = blockIdx.x * blockDim.x + threadIdx.x;
    if (i >= n) return;
    float xi[11];
#pragma unroll
    for (int k = 0; k < 11; k++) xi[k] = x[(size_t)i * 11 + k];
#pragma unroll
    for (int f = 0; f < 16; f++) {
        float acc = 0.0f;
#pragma unroll
        for (int k = 0; k < 11; k++) acc += xi[k] * sW[k * 16 + f];
        h1[(size_t)i * 16 + f] = acc;
    }
}

// ---------------- pull layers ----------------

// h2[i] = relu( pull(norm*h1) + dinv^2*h1[i] + b1 ) @ W2   (fused epilogue)
__global__ __launch_bounds__(256) void k_pull16(const int* __restrict__ off,
                                                const int2* __restrict__ edge_s,
                                                const float* __restrict__ h1,
                                                const float* __restrict__ dinv,
                                                const float* __restrict__ b1,
                                                const float* __restrict__ W2,
                                                float* __restrict__ h2, int n) {
    __shared__ float sW[32];
    __shared__ float sb[16];
    if (threadIdx.x < 32) sW[threadIdx.x] = W2[threadIdx.x];
    if (threadIdx.x < 16) sb[threadIdx.x] = b1[threadIdx.x];
    __syncthreads();
    int i = blockIdx.x * blockDim.x + threadIdx.x;
    if (i >= n) return;
    int s = off[i], e = off[i + 1];
    float dv = dinv[i];
    float cs = dv * dv;
    const float4* hi = (const float4*)(h1 + (size_t)i * 16);
    float4 a0, a1, a2, a3;
    {
        float4 h0 = hi[0], h1v = hi[1], h2v = hi[2], h3v = hi[3];
        a0 = make_float4(cs * h0.x + sb[0],  cs * h0.y + sb[1],  cs * h0.z + sb[2],  cs * h0.w + sb[3]);
        a1 = make_float4(cs * h1v.x + sb[4], cs * h1v.y + sb[5], cs * h1v.z + sb[6], cs * h1v.w + sb[7]);
        a2 = make_float4(cs * h2v.x + sb[8], cs * h2v.y + sb[9], cs * h2v.z + sb[10], cs * h2v.w + sb[11]);
        a3 = make_float4(cs * h3v.x + sb[12], cs * h3v.y + sb[13], cs * h3v.z + sb[14], cs * h3v.w + sb[15]);
    }
    for (int j = s; j < e; j++) {
        int2 ev = edge_s[j];
        int r = ev.x;
        float nw = __int_as_float(ev.y);
        const float4* hr = (const float4*)(h1 + (size_t)r * 16);
        float4 h0 = hr[0], h1v = hr[1], h2v = hr[2], h3v = hr[3];
        a0.x += nw * h0.x;  a0.y += nw * h0.y;  a0.z += nw * h0.z;  a0.w += nw * h0.w;
        a1.x += nw * h1v.x; a1.y += nw * h1v.y; a1.z += nw * h1v.z; a1.w += nw * h1v.w;
        a2.x += nw * h2v.x; a2.y += nw * h2v.y; a2.z += nw * h2v.z; a2.w += nw * h2v.w;
        a3.x += nw * h3v.x; a3.y += nw * h3v.y; a3.z += nw * h3v.z; a3.w += nw * h3v.w;
    }
    float hr_[16];
    hr_[0] = fmaxf(a0.x, 0.f); hr_[1] = fmaxf(a0.y, 0.f); hr_[2] = fmaxf(a0.z, 0.f); hr_[3] = fmaxf(a0.w, 0.f);
    hr_[4] = fmaxf(a1.x, 0.f); hr_[5] = fmaxf(a1.y, 0.f); hr_[6] = fmaxf(a1.z, 0.f); hr_[7] = fmaxf(a1.w, 0.f);
    hr_[8] = fmaxf(a2.x, 0.f); hr_[9] = fmaxf(a2.y, 0.f); hr_[10] = fmaxf(a2.z, 0.f); hr_[11] = fmaxf(a2.w, 0.f);
    hr_[12] = fmaxf(a3.x, 0.f); hr_[13] = fmaxf(a3.y, 0.f); hr_[14] = fmaxf(a3.z, 0.f); hr_[15] = fmaxf(a3.w, 0.f);
    float o0 = 0.0f, o1 = 0.0f;
#pragma unroll
    for (int f = 0; f < 16; f++) {
        o0 += hr_[f] * sW[f * 2 + 0];
        o1 += hr_[f] * sW[f * 2 + 1];
    }
    float2 ov; ov.x = o0; ov.y = o1;
    *(float2*)(h2 + (size_t)i * 2) = ov;
}

// out[i] = log_softmax( pull(norm*h2) + dinv^2*h2[i] + b2 )
__global__ __launch_bounds__(256) void k_pull2(const int* __restrict__ off,
                                               const int2* __restrict__ edge_s,
                                               const float* __restrict__ h2,
                                               const float* __restrict__ dinv,
                                               const float* __restrict__ b2,
                                               float* __restrict__ out, int n) {
    int i = blockIdx.x * blockDim.x + threadIdx.x;
    if (i >= n) return;
    int s = off[i], e = off[i + 1];
    float dv = dinv[i];
    float cs = dv * dv;
    float v0 = cs * h2[(size_t)i * 2 + 0] + b2[0];
    float v1 = cs * h2[(size_t)i * 2 + 1] + b2[1];
    for (int j = s; j < e; j++) {
        int2 ev = edge_s[j];
        int r = ev.x;
        float nw = __int_as_float(ev.y);
        float2 hv = *(const float2*)(h2 + (size_t)r * 2);
        v0 += nw * hv.x;
        v1 += nw * hv.y;
    }
    float m = fmaxf(v0, v1);
    float lse = m + logf(expf(v0 - m) + expf(v1 - m));
    float2 ov; ov.x = v0 - lse; ov.y = v1 - lse;
    *(float2*)(out + (size_t)i * 2) = ov;
}

// ---------------- fallback atomic-scatter kernels (R1 proven path) ----------------

__global__ __launch_bounds__(256) void k_init_deg(float* deg, int n) {
    int i = blockIdx.x * blockDim.x + threadIdx.x;
    if (i < n) deg[i] = 1.0f;
}

__global__ __launch_bounds__(256) void k_deg_accum(const int* __restrict__ col,
                                                   const float* __restrict__ w,
                                                   float* __restrict__ deg, int E) {
    int i = blockIdx.x * blockDim.x + threadIdx.x;
    if (i < E) atomicAdd(&deg[col[i]], w[i]);
}

__global__ __launch_bounds__(256) void k_rsqrt(float* deg, int n) {
    int i = blockIdx.x * blockDim.x + threadIdx.x;
    if (i < n) {
        float d = deg[i];
        deg[i] = (d > 0.0f) ? rsqrtf(d) : 0.0f;
    }
}

__global__ __launch_bounds__(256) void k_scatter16(const int* __restrict__ row,
                                                   const int* __restrict__ col,
                                                   const float* __restrict__ w,
                                                   const float* __restrict__ dinv,
                                                   const float* __restrict__ h1,
                                                   float* __restrict__ acc, int E) {
    int i = blockIdx.x * blockDim.x + threadIdx.x;
    if (i >= E) return;
    int r = row[i], c = col[i];
    float nw = dinv[r] * w[i] * dinv[c];
    const float4* hr = (const float4*)(h1 + (size_t)r * 16);
    float* o = acc + (size_t)c * 16;
#pragma unroll
    for (int q = 0; q < 4; q++) {
        float4 hv = hr[q];
        atomicAdd(o + q * 4 + 0, nw * hv.x);
        atomicAdd(o + q * 4 + 1, nw * hv.y);
        atomicAdd(o + q * 4 + 2, nw * hv.z);
        atomicAdd(o + q * 4 + 3, nw * hv.w);
    }
}

__global__ __launch_bounds__(256) void k_post1(const float* __restrict__ h1,
                                               const float* __restrict__ dinv,
                                               const float* __restrict__ b1,
                                               float* __restrict__ acc, int n) {
    int i = blockIdx.x * blockDim.x + threadIdx.x;
    if (i >= n) return;
    float dv = dinv[i];
    float cs = dv * dv;
#pragma unroll
    for (int f = 0; f < 16; f++) {
        float v = acc[(size_t)i * 16 + f] + cs * h1[(size_t)i * 16 + f] + b1[f];
        acc[(size_t)i * 16 + f] = v > 0.0f ? v : 0.0f;
    }
}

__global__ __launch_bounds__(256) void k_gemm2(const float* __restrict__ hrelu,
                                               const float* __restrict__ W2,
                                               float* __restrict__ h2, int n) {
    __shared__ float sW[32];
    for (int t = threadIdx.x; t < 32; t += blockDim.x) sW[t] = W2[t];
    __syncthreads();
    int i = blockIdx.x * blockDim.x + threadIdx.x;
    if (i >= n) return;
    float a0 = 0.0f, a1 = 0.0f;
#pragma unroll
    for (int f = 0; f < 16; f++) {
        float h = hrelu[(size_t)i * 16 + f];
        a0 += h * sW[f * 2 + 0];
        a1 += h * sW[f * 2 + 1];
    }
    h2[(size_t)i * 2 + 0] = a0;
    h2[(size_t)i * 2 + 1] = a1;
}

__global__ __launch_bounds__(256) void k_scatter2(const int* __restrict__ row,
                                                  const int* __restrict__ col,
                                                  const float* __restrict__ w,
                                                  const float* __restrict__ dinv,
                                                  const float* __restrict__ h2,
                                                  float* __restrict__ out, int E) {
    int i = blockIdx.x * blockDim.x + threadIdx.x;
    if (i >= E) return;
    int r = row[i], c = col[i];
    float nw = dinv[r] * w[i] * dinv[c];
    atomicAdd(&out[(size_t)c * 2 + 0], nw * h2[(size_t)r * 2 + 0]);
    atomicAdd(&out[(size_t)c * 2 + 1], nw * h2[(size_t)r * 2 + 1]);
}

__global__ __launch_bounds__(256) void k_final(const float* __restrict__ h2,
                                               const float* __restrict__ dinv,
                                               const float* __restrict__ b2,
                                               float* __restrict__ out, int n) {
    int i = blockIdx.x * blockDim.x + threadIdx.x;
    if (i >= n) return;
    float dv = dinv[i];
    float cs = dv * dv;
    float v0 = out[(size_t)i * 2 + 0] + cs * h2[(size_t)i * 2 + 0] + b2[0];
    float v1 = out[(size_t)i * 2 + 1] + cs * h2[(size_t)i * 2 + 1] + b2[1];
    float m = fmaxf(v0, v1);
    float lse = m + logf(expf(v0 - m) + expf(v1 - m));
    out[(size_t)i * 2 + 0] = v0 - lse;
    out[(size_t)i * 2 + 1] = v1 - lse;
}

// ---------------- launch ----------------

static inline size_t align64(size_t x) { return (x + 63) & ~(size_t)63; }

extern "C" void kernel_launch(void* const* d_in, const int* in_sizes, int n_in,
                              void* d_out, int out_size, void* d_ws, size_t ws_size,
                              hipStream_t stream) {
    const float* x  = (const float*)d_in[0];
    const int*   ei = (const int*)d_in[1];
    const float* ew = (const float*)d_in[2];
    const float* W1 = (const float*)d_in[3];
    const float* b1 = (const float*)d_in[4];
    const float* W2 = (const float*)d_in[5];
    const float* b2 = (const float*)d_in[6];

    const int n = in_sizes[0] / 11;
    const int E = in_sizes[2];
    const int* rowp = ei;       // sources
    const int* colp = ei + E;   // targets

    const int TB = 256;
    const int gN = (n + TB - 1) / TB;
    const int gE = (E + TB - 1) / TB;
    const int nb = (n + 255) / 256;

    // --- workspace layout ---
    char* base = (char*)d_ws;
    size_t o_pack = 0;                                        // u64 n
    size_t o_dinv = align64(o_pack + (size_t)n * 8);          // float n
    size_t o_rank = align64(o_dinv + (size_t)n * 4);          // u16 E
    size_t o_off  = align64(o_rank + (size_t)E * 2);          // int n+1
    size_t o_bsum = align64(o_off + (size_t)(n + 1) * 4);     // int nb
    size_t o_h1   = align64(o_bsum + (size_t)nb * 4);         // float 16n
    size_t o_edge = align64(o_h1 + (size_t)n * 16 * 4);       // int2 E
    size_t o_h2   = align64(o_edge + (size_t)E * 8);          // float 2n
    size_t needed = align64(o_h2 + (size_t)n * 2 * 4);

    float* outf = (float*)d_out;

    if (ws_size >= needed) {
        u64*            packed = (u64*)(base + o_pack);
        float*          dinv   = (float*)(base + o_dinv);
        unsigned short* rank   = (unsigned short*)(base + o_rank);
        int*            off    = (int*)(base + o_off);
        int*            bsum   = (int*)(base + o_bsum);
        float*          h1     = (float*)(base + o_h1);
        int2*           edge_s = (int2*)(base + o_edge);
        float*          h2     = (float*)(base + o_h2);

        hipMemsetAsync(packed, 0, (size_t)n * 8, stream);
        k_hist_pack<<<gE, TB, 0, stream>>>(colp, ew, packed, rank, E);
        k_unpack<<<gN, TB, 0, stream>>>(packed, dinv, n);
        k_scan_local<<<nb, 256, 0, stream>>>(packed, off, bsum, n);
        k_scan_sums<<<1, 256, 0, stream>>>(bsum, nb);
        k_scan_add<<<nb, 256, 0, stream>>>(off, bsum, n, E);
        k_gemm1<<<gN, TB, 0, stream>>>(x, W1, h1, n);   // overlap-friendly placement
        k_reorder<<<gE, TB, 0, stream>>>(rowp, colp, ew, dinv, off, rank, edge_s, E);

        k_pull16<<<gN, TB, 0, stream>>>(off, edge_s, h1, dinv, b1, W2, h2, n);
        k_pull2<<<gN, TB, 0, stream>>>(off, edge_s, h2, dinv, b2, outf, n);
    } else {
        // fallback: atomic-scatter path (R1)
        float* ws   = (float*)d_ws;
        float* dinv = ws;
        float* h1   = ws + (size_t)n;
        float* acc1 = ws + (size_t)n * 17;

        k_init_deg<<<gN, TB, 0, stream>>>(dinv, n);
        k_deg_accum<<<gE, TB, 0, stream>>>(colp, ew, dinv, E);
        k_rsqrt<<<gN, TB, 0, stream>>>(dinv, n);

        k_gemm1<<<gN, TB, 0, stream>>>(x, W1, h1, n);
        hipMemsetAsync(acc1, 0, (size_t)n * 16 * sizeof(float), stream);
        k_scatter16<<<gE, TB, 0, stream>>>(rowp, colp, ew, dinv, h1, acc1, E);
        k_post1<<<gN, TB, 0, stream>>>(h1, dinv, b1, acc1, n);

        float* h2 = h1;
        k_gemm2<<<gN, TB, 0, stream>>>(acc1, W2, h2, n);
        hipMemsetAsync(outf, 0, (size_t)n * 2 * sizeof(float), stream);
        k_scatter2<<<gE, TB, 0, stream>>>(rowp, colp, ew, dinv, h2, outf, E);
        k_final<<<gN, TB, 0, stream>>>(h2, dinv, b2, outf, n);
    }
}

// Round 4
// 2299.174 us; speedup vs baseline: 6.7987x; 1.0955x over previous
//
#include <hip/hip_runtime.h>
#include <math.h>

// ---------------------------------------------------------------------------
// 2-layer GCN forward, CSR-pull, dinv folded into node features:
//   k_hist_pack : ONE u64 atomic per edge -> (cnt<<32 | fixp(w)), rank = ret>>32
//   k_unpack    : dinv = rsqrt(1 + fixp^-1(low32))
//   scan(cnt)   : CSR offsets
//   k_reorder   : NO atomics, NO gathers except off[col]; edge_s[pos]={row,w}
//   k_gemm1     : h1s[i] = dinv[i] * (x[i] @ W1)
//   k_pull16    : a = sum_e w*h1s[row] + h1s[i]; hrelu = relu(dinv[i]*a + b1);
//                 h2s[i] = dinv[i] * (hrelu @ W2)        (fused epilogue)
//   k_pull2     : v = dinv[i]*(sum_e w*h2s[row] + h2s[i]) + b2; log_softmax
// Fallback to R1 atomic-scatter path if workspace is too small.
// ---------------------------------------------------------------------------

#define FIXP_SCALE 8388608.0f          // 2^23
#define FIXP_INV   (1.0f / 8388608.0f)

typedef unsigned long long u64;

// ---------------- CSR build ----------------

__global__ __launch_bounds__(256) void k_hist_pack(const int* __restrict__ col,
                                                   const float* __restrict__ w,
                                                   u64* __restrict__ packed,
                                                   unsigned short* __restrict__ rank,
                                                   int E) {
    int i = blockIdx.x * blockDim.x + threadIdx.x;
    if (i >= E) return;
    int c = col[i];
    u64 add = ((u64)1 << 32) | (u64)(unsigned int)(w[i] * FIXP_SCALE + 0.5f);
    u64 old = atomicAdd(&packed[c], add);
    rank[i] = (unsigned short)(old >> 32);
}

__global__ __launch_bounds__(256) void k_unpack(const u64* __restrict__ packed,
                                                float* __restrict__ dinv, int n) {
    int i = blockIdx.x * blockDim.x + threadIdx.x;
    if (i >= n) return;
    float deg = 1.0f + (float)(unsigned int)(packed[i] & 0xffffffffu) * FIXP_INV;
    dinv[i] = rsqrtf(deg);   // deg >= 1 always (self-loop)
}

// block-local exclusive scan of cnt (= packed>>32); block totals to bsum
__global__ __launch_bounds__(256) void k_scan_local(const u64* __restrict__ packed,
                                                    int* __restrict__ out,
                                                    int* __restrict__ bsum, int n) {
    __shared__ int s[256];
    int t = threadIdx.x;
    int i = blockIdx.x * 256 + t;
    int v = (i < n) ? (int)(packed[i] >> 32) : 0;
    s[t] = v;
    __syncthreads();
    for (int off = 1; off < 256; off <<= 1) {
        int u = (t >= off) ? s[t - off] : 0;
        __syncthreads();
        s[t] += u;
        __syncthreads();
    }
    if (i < n) out[i] = s[t] - v;          // exclusive
    if (t == 255) bsum[blockIdx.x] = s[255];
}

__global__ __launch_bounds__(256) void k_scan_sums(int* __restrict__ bsum, int nb) {
    __shared__ int s[256];
    __shared__ int carry;
    int t = threadIdx.x;
    if (t == 0) carry = 0;
    __syncthreads();
    int chunks = (nb + 255) / 256;
    for (int ch = 0; ch < chunks; ch++) {
        int i = ch * 256 + t;
        int v = (i < nb) ? bsum[i] : 0;
        s[t] = v;
        __syncthreads();
        for (int off = 1; off < 256; off <<= 1) {
            int u = (t >= off) ? s[t - off] : 0;
            __syncthreads();
            s[t] += u;
            __syncthreads();
        }
        int incl = s[t];
        int my_carry = carry;
        if (i < nb) bsum[i] = incl - v + my_carry;
        __syncthreads();
        if (t == 0) carry = my_carry + s[255];
        __syncthreads();
    }
}

__global__ __launch_bounds__(256) void k_scan_add(int* __restrict__ off,
                                                  const int* __restrict__ bsum,
                                                  int n, int E) {
    int t = threadIdx.x;
    int i = blockIdx.x * 256 + t;
    if (i < n) off[i] += bsum[blockIdx.x];
    if (i == 0) off[n] = E;
}

// pure permutation: pos = off[c] + rank[i]; edge_s[pos] = {row, w} (8B store)
__global__ __launch_bounds__(256) void k_reorder(const int* __restrict__ row,
                                                 const int* __restrict__ col,
                                                 const float* __restrict__ w,
                                                 const int* __restrict__ off,
                                                 const unsigned short* __restrict__ rank,
                                                 int2* __restrict__ edge_s, int E) {
    int i = blockIdx.x * blockDim.x + threadIdx.x;
    if (i >= E) return;
    int c = col[i];
    int pos = off[c] + (int)rank[i];
    int2 v;
    v.x = row[i];
    v.y = __float_as_int(w[i]);
    edge_s[pos] = v;
}

// ---------------- dense layer ----------------

// h1s[i][0..15] = dinv[i] * (x[i][0..10] @ W1(11x16))
__global__ __launch_bounds__(256) void k_gemm1(const float* __restrict__ x,
                                               const float* __restrict__ W1,
                                               const float* __restrict__ dinv,
                                               float* __restrict__ h1s, int n) {
    __shared__ float sW[11 * 16];
    for (int t = threadIdx.x; t < 11 * 16; t += blockDim.x) sW[t] = W1[t];
    __syncthreads();
    int i = blockIdx.x * blockDim.x + threadIdx.x;
    if (i >= n) return;
    float xi[11];
#pragma unroll
    for (int k = 0; k < 11; k++) xi[k] = x[(size_t)i * 11 + k];
    float dv = dinv[i];
#pragma unroll
    for (int f = 0; f < 16; f++) {
        float acc = 0.0f;
#pragma unroll
        for (int k = 0; k < 11; k++) acc += xi[k] * sW[k * 16 + f];
        h1s[(size_t)i * 16 + f] = dv * acc;
    }
}

// ---------------- pull layers ----------------

// a = sum_e w*h1s[row] + h1s[i]; hrelu = relu(dinv*a + b1); h2s = dinv*(hrelu@W2)
__global__ __launch_bounds__(256) void k_pull16(const int* __restrict__ off,
                                                const int2* __restrict__ edge_s,
                                                const float* __restrict__ h1s,
                                                const float* __restrict__ dinv,
                                                const float* __restrict__ b1,
                                                const float* __restrict__ W2,
                                                float* __restrict__ h2s, int n) {
    __shared__ float sW[32];
    __shared__ float sb[16];
    if (threadIdx.x < 32) sW[threadIdx.x] = W2[threadIdx.x];
    if (threadIdx.x < 16) sb[threadIdx.x] = b1[threadIdx.x];
    __syncthreads();
    int i = blockIdx.x * blockDim.x + threadIdx.x;
    if (i >= n) return;
    int s = off[i], e = off[i + 1];
    const float4* hi = (const float4*)(h1s + (size_t)i * 16);
    float4 a0 = hi[0], a1 = hi[1], a2 = hi[2], a3 = hi[3];   // self-loop term
    for (int j = s; j < e; j++) {
        int2 ev = edge_s[j];
        int r = ev.x;
        float nw = __int_as_float(ev.y);
        const float4* hr = (const float4*)(h1s + (size_t)r * 16);
        float4 h0 = hr[0], h1v = hr[1], h2v = hr[2], h3v = hr[3];
        a0.x += nw * h0.x;  a0.y += nw * h0.y;  a0.z += nw * h0.z;  a0.w += nw * h0.w;
        a1.x += nw * h1v.x; a1.y += nw * h1v.y; a1.z += nw * h1v.z; a1.w += nw * h1v.w;
        a2.x += nw * h2v.x; a2.y += nw * h2v.y; a2.z += nw * h2v.z; a2.w += nw * h2v.w;
        a3.x += nw * h3v.x; a3.y += nw * h3v.y; a3.z += nw * h3v.z; a3.w += nw * h3v.w;
    }
    float dv = dinv[i];
    float hr_[16];
    hr_[0] = fmaxf(dv * a0.x + sb[0], 0.f);  hr_[1] = fmaxf(dv * a0.y + sb[1], 0.f);
    hr_[2] = fmaxf(dv * a0.z + sb[2], 0.f);  hr_[3] = fmaxf(dv * a0.w + sb[3], 0.f);
    hr_[4] = fmaxf(dv * a1.x + sb[4], 0.f);  hr_[5] = fmaxf(dv * a1.y + sb[5], 0.f);
    hr_[6] = fmaxf(dv * a1.z + sb[6], 0.f);  hr_[7] = fmaxf(dv * a1.w + sb[7], 0.f);
    hr_[8] = fmaxf(dv * a2.x + sb[8], 0.f);  hr_[9] = fmaxf(dv * a2.y + sb[9], 0.f);
    hr_[10] = fmaxf(dv * a2.z + sb[10], 0.f); hr_[11] = fmaxf(dv * a2.w + sb[11], 0.f);
    hr_[12] = fmaxf(dv * a3.x + sb[12], 0.f); hr_[13] = fmaxf(dv * a3.y + sb[13], 0.f);
    hr_[14] = fmaxf(dv * a3.z + sb[14], 0.f); hr_[15] = fmaxf(dv * a3.w + sb[15], 0.f);
    float o0 = 0.0f, o1 = 0.0f;
#pragma unroll
    for (int f = 0; f < 16; f++) {
        o0 += hr_[f] * sW[f * 2 + 0];
        o1 += hr_[f] * sW[f * 2 + 1];
    }
    float2 ov; ov.x = dv * o0; ov.y = dv * o1;   // h2s = dinv * h2
    *(float2*)(h2s + (size_t)i * 2) = ov;
}

// v = dinv*(sum_e w*h2s[row] + h2s[i]) + b2; out = log_softmax(v)
__global__ __launch_bounds__(256) void k_pull2(const int* __restrict__ off,
                                               const int2* __restrict__ edge_s,
                                               const float* __restrict__ h2s,
                                               const float* __restrict__ dinv,
                                               const float* __restrict__ b2,
                                               float* __restrict__ out, int n) {
    int i = blockIdx.x * blockDim.x + threadIdx.x;
    if (i >= n) return;
    int s = off[i], e = off[i + 1];
    float2 self = *(const float2*)(h2s + (size_t)i * 2);
    float a0 = self.x, a1 = self.y;
    for (int j = s; j < e; j++) {
        int2 ev = edge_s[j];
        int r = ev.x;
        float nw = __int_as_float(ev.y);
        float2 hv = *(const float2*)(h2s + (size_t)r * 2);
        a0 += nw * hv.x;
        a1 += nw * hv.y;
    }
    float dv = dinv[i];
    float v0 = dv * a0 + b2[0];
    float v1 = dv * a1 + b2[1];
    float m = fmaxf(v0, v1);
    float lse = m + logf(expf(v0 - m) + expf(v1 - m));
    float2 ov; ov.x = v0 - lse; ov.y = v1 - lse;
    *(float2*)(out + (size_t)i * 2) = ov;
}

// ---------------- fallback atomic-scatter kernels (R1 proven path) ----------------

__global__ __launch_bounds__(256) void k_init_deg(float* deg, int n) {
    int i = blockIdx.x * blockDim.x + threadIdx.x;
    if (i < n) deg[i] = 1.0f;
}

__global__ __launch_bounds__(256) void k_deg_accum(const int* __restrict__ col,
                                                   const float* __restrict__ w,
                                                   float* __restrict__ deg, int E) {
    int i = blockIdx.x * blockDim.x + threadIdx.x;
    if (i < E) atomicAdd(&deg[col[i]], w[i]);
}

__global__ __launch_bounds__(256) void k_rsqrt(float* deg, int n) {
    int i = blockIdx.x * blockDim.x + threadIdx.x;
    if (i < n) {
        float d = deg[i];
        deg[i] = (d > 0.0f) ? rsqrtf(d) : 0.0f;
    }
}

__global__ __launch_bounds__(256) void k_gemm1_plain(const float* __restrict__ x,
                                                     const float* __restrict__ W1,
                                                     float* __restrict__ h1, int n) {
    __shared__ float sW[11 * 16];
    for (int t = threadIdx.x; t < 11 * 16; t += blockDim.x) sW[t] = W1[t];
    __syncthreads();
    int i = blockIdx.x * blockDim.x + threadIdx.x;
    if (i >= n) return;
    float xi[11];
#pragma unroll
    for (int k = 0; k < 11; k++) xi[k] = x[(size_t)i * 11 + k];
#pragma unroll
    for (int f = 0; f < 16; f++) {
        float acc = 0.0f;
#pragma unroll
        for (int k = 0; k < 11; k++) acc += xi[k] * sW[k * 16 + f];
        h1[(size_t)i * 16 + f] = acc;
    }
}

__global__ __launch_bounds__(256) void k_scatter16(const int* __restrict__ row,
                                                   const int* __restrict__ col,
                                                   const float* __restrict__ w,
                                                   const float* __restrict__ dinv,
                                                   const float* __restrict__ h1,
                                                   float* __restrict__ acc, int E) {
    int i = blockIdx.x * blockDim.x + threadIdx.x;
    if (i >= E) return;
    int r = row[i], c = col[i];
    float nw = dinv[r] * w[i] * dinv[c];
    const float4* hr = (const float4*)(h1 + (size_t)r * 16);
    float* o = acc + (size_t)c * 16;
#pragma unroll
    for (int q = 0; q < 4; q++) {
        float4 hv = hr[q];
        atomicAdd(o + q * 4 + 0, nw * hv.x);
        atomicAdd(o + q * 4 + 1, nw * hv.y);
        atomicAdd(o + q * 4 + 2, nw * hv.z);
        atomicAdd(o + q * 4 + 3, nw * hv.w);
    }
}

__global__ __launch_bounds__(256) void k_post1(const float* __restrict__ h1,
                                               const float* __restrict__ dinv,
                                               const float* __restrict__ b1,
                                               float* __restrict__ acc, int n) {
    int i = blockIdx.x * blockDim.x + threadIdx.x;
    if (i >= n) return;
    float dv = dinv[i];
    float cs = dv * dv;
#pragma unroll
    for (int f = 0; f < 16; f++) {
        float v = acc[(size_t)i * 16 + f] + cs * h1[(size_t)i * 16 + f] + b1[f];
        acc[(size_t)i * 16 + f] = v > 0.0f ? v : 0.0f;
    }
}

__global__ __launch_bounds__(256) void k_gemm2(const float* __restrict__ hrelu,
                                               const float* __restrict__ W2,
                                               float* __restrict__ h2, int n) {
    __shared__ float sW[32];
    for (int t = threadIdx.x; t < 32; t += blockDim.x) sW[t] = W2[t];
    __syncthreads();
    int i = blockIdx.x * blockDim.x + threadIdx.x;
    if (i >= n) return;
    float a0 = 0.0f, a1 = 0.0f;
#pragma unroll
    for (int f = 0; f < 16; f++) {
        float h = hrelu[(size_t)i * 16 + f];
        a0 += h * sW[f * 2 + 0];
        a1 += h * sW[f * 2 + 1];
    }
    h2[(size_t)i * 2 + 0] = a0;
    h2[(size_t)i * 2 + 1] = a1;
}

__global__ __launch_bounds__(256) void k_scatter2(const int* __restrict__ row,
                                                  const int* __restrict__ col,
                                                  const float* __restrict__ w,
                                                  const float* __restrict__ dinv,
                                                  const float* __restrict__ h2,
                                                  float* __restrict__ out, int E) {
    int i = blockIdx.x * blockDim.x + threadIdx.x;
    if (i >= E) return;
    int r = row[i], c = col[i];
    float nw = dinv[r] * w[i] * dinv[c];
    atomicAdd(&out[(size_t)c * 2 + 0], nw * h2[(size_t)r * 2 + 0]);
    atomicAdd(&out[(size_t)c * 2 + 1], nw * h2[(size_t)r * 2 + 1]);
}

__global__ __launch_bounds__(256) void k_final(const float* __restrict__ h2,
                                               const float* __restrict__ dinv,
                                               const float* __restrict__ b2,
                                               float* __restrict__ out, int n) {
    int i = blockIdx.x * blockDim.x + threadIdx.x;
    if (i >= n) return;
    float dv = dinv[i];
    float cs = dv * dv;
    float v0 = out[(size_t)i * 2 + 0] + cs * h2[(size_t)i * 2 + 0] + b2[0];
    float v1 = out[(size_t)i * 2 + 1] + cs * h2[(size_t)i * 2 + 1] + b2[1];
    float m = fmaxf(v0, v1);
    float lse = m + logf(expf(v0 - m) + expf(v1 - m));
    out[(size_t)i * 2 + 0] = v0 - lse;
    out[(size_t)i * 2 + 1] = v1 - lse;
}

// ---------------- launch ----------------

static inline size_t align64(size_t x) { return (x + 63) & ~(size_t)63; }

extern "C" void kernel_launch(void* const* d_in, const int* in_sizes, int n_in,
                              void* d_out, int out_size, void* d_ws, size_t ws_size,
                              hipStream_t stream) {
    const float* x  = (const float*)d_in[0];
    const int*   ei = (const int*)d_in[1];
    const float* ew = (const float*)d_in[2];
    const float* W1 = (const float*)d_in[3];
    const float* b1 = (const float*)d_in[4];
    const float* W2 = (const float*)d_in[5];
    const float* b2 = (const float*)d_in[6];

    const int n = in_sizes[0] / 11;
    const int E = in_sizes[2];
    const int* rowp = ei;       // sources
    const int* colp = ei + E;   // targets

    const int TB = 256;
    const int gN = (n + TB - 1) / TB;
    const int gE = (E + TB - 1) / TB;
    const int nb = (n + 255) / 256;

    // --- workspace layout ---
    char* base = (char*)d_ws;
    size_t o_pack = 0;                                        // u64 n
    size_t o_dinv = align64(o_pack + (size_t)n * 8);          // float n
    size_t o_rank = align64(o_dinv + (size_t)n * 4);          // u16 E
    size_t o_off  = align64(o_rank + (size_t)E * 2);          // int n+1
    size_t o_bsum = align64(o_off + (size_t)(n + 1) * 4);     // int nb
    size_t o_h1   = align64(o_bsum + (size_t)nb * 4);         // float 16n
    size_t o_edge = align64(o_h1 + (size_t)n * 16 * 4);       // int2 E
    size_t o_h2   = align64(o_edge + (size_t)E * 8);          // float 2n
    size_t needed = align64(o_h2 + (size_t)n * 2 * 4);

    float* outf = (float*)d_out;

    if (ws_size >= needed) {
        u64*            packed = (u64*)(base + o_pack);
        float*          dinv   = (float*)(base + o_dinv);
        unsigned short* rank   = (unsigned short*)(base + o_rank);
        int*            off    = (int*)(base + o_off);
        int*            bsum   = (int*)(base + o_bsum);
        float*          h1s    = (float*)(base + o_h1);
        int2*           edge_s = (int2*)(base + o_edge);
        float*          h2s    = (float*)(base + o_h2);

        hipMemsetAsync(packed, 0, (size_t)n * 8, stream);
        k_hist_pack<<<gE, TB, 0, stream>>>(colp, ew, packed, rank, E);
        k_unpack<<<gN, TB, 0, stream>>>(packed, dinv, n);
        k_scan_local<<<nb, 256, 0, stream>>>(packed, off, bsum, n);
        k_scan_sums<<<1, 256, 0, stream>>>(bsum, nb);
        k_scan_add<<<nb, 256, 0, stream>>>(off, bsum, n, E);
        k_reorder<<<gE, TB, 0, stream>>>(rowp, colp, ew, off, rank, edge_s, E);
        k_gemm1<<<gN, TB, 0, stream>>>(x, W1, dinv, h1s, n);

        k_pull16<<<gN, TB, 0, stream>>>(off, edge_s, h1s, dinv, b1, W2, h2s, n);
        k_pull2<<<gN, TB, 0, stream>>>(off, edge_s, h2s, dinv, b2, outf, n);
    } else {
        // fallback: atomic-scatter path (R1)
        float* ws   = (float*)d_ws;
        float* dinv = ws;
        float* h1   = ws + (size_t)n;
        float* acc1 = ws + (size_t)n * 17;

        k_init_deg<<<gN, TB, 0, stream>>>(dinv, n);
        k_deg_accum<<<gE, TB, 0, stream>>>(colp, ew, dinv, E);
        k_rsqrt<<<gN, TB, 0, stream>>>(dinv, n);

        k_gemm1_plain<<<gN, TB, 0, stream>>>(x, W1, h1, n);
        hipMemsetAsync(acc1, 0, (size_t)n * 16 * sizeof(float), stream);
        k_scatter16<<<gE, TB, 0, stream>>>(rowp, colp, ew, dinv, h1, acc1, E);
        k_post1<<<gN, TB, 0, stream>>>(h1, dinv, b1, acc1, n);

        float* h2 = h1;
        k_gemm2<<<gN, TB, 0, stream>>>(acc1, W2, h2, n);
        hipMemsetAsync(outf, 0, (size_t)n * 2 * sizeof(float), stream);
        k_scatter2<<<gE, TB, 0, stream>>>(rowp, colp, ew, dinv, h2, outf, E);
        k_final<<<gN, TB, 0, stream>>>(h2, dinv, b2, outf, n);
    }
}

// Round 5
// 2216.054 us; speedup vs baseline: 7.0537x; 1.0375x over previous
//
#include <hip/hip_runtime.h>
#include <math.h>

// ---------------------------------------------------------------------------
// 2-layer GCN forward — bucketed counting-split, ZERO global atomics.
//   Buckets of 512 target nodes (NB = ceil(n/512) <= 1024).
//   k_count      : per-block LDS histogram over buckets -> hist_g (coalesced)
//   scan         : hierarchical exclusive scan in bucket-major logical order
//                  -> base_g[(bucket,partblk)] scatter bases
//   k_scatter    : LDS cursors; edge_g[pos] = pack{w:32|collow:9|row:19}
//   k_prep       : per-bucket degw (LDS f32 atomics) -> dinv; fused gemm1:
//                  h1s = dinv * (x @ W1)
//   k_pull16_b   : per-bucket LDS acc[512][16]; stream edges, gather h1s[row],
//                  LDS-atomic accumulate; epilogue relu(dv*a+b1) @ W2 -> h2s
//   k_pull2_b    : per-bucket LDS acc[512][2]; same, epilogue log_softmax->out
// Fallback to the R1 atomic-scatter path if ws too small / n too large.
// ---------------------------------------------------------------------------

typedef unsigned long long u64;
typedef unsigned int u32;

#define BKT    512        // nodes per bucket (collow = 9 bits)
#define NBMAX  1024       // max buckets (=> n <= 2^19, matches row:19 packing)
#define NBLK   512        // partition blocks for count/scatter

// ---------------- count / scan / scatter ----------------

__global__ __launch_bounds__(256) void k_count(const int* __restrict__ col,
                                               u32* __restrict__ hist_g,
                                               int NB, int E, int CH) {
    __shared__ u32 cnt[NBMAX];
    for (int b = threadIdx.x; b < NB; b += 256) cnt[b] = 0;
    __syncthreads();
    int blk = blockIdx.x;
    int s = blk * CH, e = min(s + CH, E);
    for (int i = s + threadIdx.x; i < e; i += 256)
        atomicAdd(&cnt[col[i] >> 9], 1u);          // LDS atomic
    __syncthreads();
    for (int b = threadIdx.x; b < NB; b += 256)
        hist_g[(size_t)blk * NB + b] = cnt[b];     // coalesced
}

// logical index e = bucket*NBLK + blk ; physical = blk*NB + bucket
__global__ __launch_bounds__(256) void k_scan_local32(const u32* __restrict__ hist_g,
                                                      u32* __restrict__ base_g,
                                                      u32* __restrict__ bsum,
                                                      int NB, int M) {
    __shared__ u32 s[256];
    int t = threadIdx.x;
    int e = blockIdx.x * 256 + t;
    u32 v = 0;
    if (e < M) {
        int b = e / NBLK, blk = e % NBLK;
        v = hist_g[(size_t)blk * NB + b];
    }
    s[t] = v;
    __syncthreads();
    for (int off = 1; off < 256; off <<= 1) {
        u32 u = (t >= off) ? s[t - off] : 0;
        __syncthreads();
        s[t] += u;
        __syncthreads();
    }
    if (e < M) base_g[e] = s[t] - v;               // exclusive
    if (t == 255) bsum[blockIdx.x] = s[255];
}

__global__ __launch_bounds__(256) void k_scan_sums32(u32* __restrict__ bsum, int nb) {
    __shared__ u32 s[256];
    __shared__ u32 carry;
    int t = threadIdx.x;
    if (t == 0) carry = 0;
    __syncthreads();
    int chunks = (nb + 255) / 256;
    for (int ch = 0; ch < chunks; ch++) {
        int i = ch * 256 + t;
        u32 v = (i < nb) ? bsum[i] : 0;
        s[t] = v;
        __syncthreads();
        for (int off = 1; off < 256; off <<= 1) {
            u32 u = (t >= off) ? s[t - off] : 0;
            __syncthreads();
            s[t] += u;
            __syncthreads();
        }
        u32 incl = s[t];
        u32 my_carry = carry;
        if (i < nb) bsum[i] = incl - v + my_carry;
        __syncthreads();
        if (t == 0) carry = my_carry + s[255];
        __syncthreads();
    }
}

__global__ __launch_bounds__(256) void k_scan_add32(u32* __restrict__ base_g,
                                                    const u32* __restrict__ bsum,
                                                    int M) {
    int e = blockIdx.x * 256 + threadIdx.x;
    if (e < M) base_g[e] += bsum[blockIdx.x];
}

__global__ __launch_bounds__(256) void k_scatter(const int* __restrict__ row,
                                                 const int* __restrict__ col,
                                                 const float* __restrict__ w,
                                                 const u32* __restrict__ base_g,
                                                 u64* __restrict__ edge_g,
                                                 int NB, int E, int CH) {
    __shared__ u32 cursor[NBMAX];
    int blk = blockIdx.x;
    for (int b = threadIdx.x; b < NB; b += 256)
        cursor[b] = base_g[(size_t)b * NBLK + blk];
    __syncthreads();
    int s = blk * CH, e = min(s + CH, E);
    for (int i = s + threadIdx.x; i < e; i += 256) {
        int c = col[i];
        int b = c >> 9;
        u32 pos = atomicAdd(&cursor[b], 1u);       // LDS atomic
        u64 rec = ((u64)__float_as_uint(w[i]) << 32)
                | ((u64)(u32)(c & 511) << 19) | (u64)(u32)row[i];
        edge_g[pos] = rec;
    }
}

// ---------------- prep: deg -> dinv, fused gemm1 ----------------

__global__ __launch_bounds__(256) void k_prep(const u64* __restrict__ edge_g,
                                              const u32* __restrict__ base_g,
                                              const float* __restrict__ x,
                                              const float* __restrict__ W1,
                                              float* __restrict__ dinv_g,
                                              float* __restrict__ h1s,
                                              int NB, int n, int E) {
    __shared__ float degw[BKT];
    __shared__ float sW[176];
    int b = blockIdx.x;
    for (int j = threadIdx.x; j < BKT; j += 256) degw[j] = 1.0f;  // self-loop
    for (int t = threadIdx.x; t < 176; t += 256) sW[t] = W1[t];
    __syncthreads();
    int s = (int)base_g[(size_t)b * NBLK];
    int e = (b + 1 < NB) ? (int)base_g[(size_t)(b + 1) * NBLK] : E;
    for (int i = s + threadIdx.x; i < e; i += 256) {
        u64 rec = edge_g[i];
        int cl = (int)(((u32)rec >> 19) & 511u);
        float wv = __uint_as_float((u32)(rec >> 32));
        atomicAdd(&degw[cl], wv);                  // LDS f32 atomic
    }
    __syncthreads();
    int node0 = b << 9;
    int nn = min(BKT, n - node0);
    for (int j = threadIdx.x; j < nn; j += 256) {
        int node = node0 + j;
        float dv = rsqrtf(degw[j]);
        dinv_g[node] = dv;
        float xi[11];
#pragma unroll
        for (int k = 0; k < 11; k++) xi[k] = x[(size_t)node * 11 + k];
#pragma unroll
        for (int f = 0; f < 16; f++) {
            float a = 0.f;
#pragma unroll
            for (int k = 0; k < 11; k++) a += xi[k] * sW[k * 16 + f];
            h1s[(size_t)node * 16 + f] = dv * a;
        }
    }
}

// ---------------- bucketed pull layers ----------------

__global__ __launch_bounds__(256) void k_pull16_b(const u64* __restrict__ edge_g,
                                                  const u32* __restrict__ base_g,
                                                  const float* __restrict__ h1s,
                                                  const float* __restrict__ dinv_g,
                                                  const float* __restrict__ b1,
                                                  const float* __restrict__ W2,
                                                  float* __restrict__ h2s,
                                                  int NB, int n, int E) {
    __shared__ float acc[BKT * 16];   // 32 KB
    __shared__ float sW[32];
    __shared__ float sb[16];
    if (threadIdx.x < 32) sW[threadIdx.x] = W2[threadIdx.x];
    if (threadIdx.x < 16) sb[threadIdx.x] = b1[threadIdx.x];
    int b = blockIdx.x;
    int node0 = b << 9;
    int nn = min(BKT, n - node0);
    for (int t = threadIdx.x; t < nn * 16; t += 256)
        acc[t] = h1s[(size_t)node0 * 16 + t];      // init with self term
    __syncthreads();
    int s = (int)base_g[(size_t)b * NBLK];
    int e = (b + 1 < NB) ? (int)base_g[(size_t)(b + 1) * NBLK] : E;
    for (int i = s + threadIdx.x; i < e; i += 256) {
        u64 rec = edge_g[i];
        int r  = (int)((u32)rec & 0x7FFFFu);
        int cl = (int)(((u32)rec >> 19) & 511u);
        float wv = __uint_as_float((u32)(rec >> 32));
        const float4* hr = (const float4*)(h1s + (size_t)r * 16);
        float4 h0 = hr[0], h1v = hr[1], h2v = hr[2], h3v = hr[3];
        float* a = acc + cl * 16;
        atomicAdd(a + 0,  wv * h0.x);  atomicAdd(a + 1,  wv * h0.y);
        atomicAdd(a + 2,  wv * h0.z);  atomicAdd(a + 3,  wv * h0.w);
        atomicAdd(a + 4,  wv * h1v.x); atomicAdd(a + 5,  wv * h1v.y);
        atomicAdd(a + 6,  wv * h1v.z); atomicAdd(a + 7,  wv * h1v.w);
        atomicAdd(a + 8,  wv * h2v.x); atomicAdd(a + 9,  wv * h2v.y);
        atomicAdd(a + 10, wv * h2v.z); atomicAdd(a + 11, wv * h2v.w);
        atomicAdd(a + 12, wv * h3v.x); atomicAdd(a + 13, wv * h3v.y);
        atomicAdd(a + 14, wv * h3v.z); atomicAdd(a + 15, wv * h3v.w);
    }
    __syncthreads();
    for (int j = threadIdx.x; j < nn; j += 256) {
        int node = node0 + j;
        float dv = dinv_g[node];
        float o0 = 0.f, o1 = 0.f;
#pragma unroll
        for (int f = 0; f < 16; f++) {
            float hrl = fmaxf(dv * acc[j * 16 + f] + sb[f], 0.f);
            o0 += hrl * sW[f * 2 + 0];
            o1 += hrl * sW[f * 2 + 1];
        }
        float2 ov; ov.x = dv * o0; ov.y = dv * o1;  // h2s = dinv * h2
        *(float2*)(h2s + (size_t)node * 2) = ov;
    }
}

__global__ __launch_bounds__(256) void k_pull2_b(const u64* __restrict__ edge_g,
                                                 const u32* __restrict__ base_g,
                                                 const float* __restrict__ h2s,
                                                 const float* __restrict__ dinv_g,
                                                 const float* __restrict__ b2,
                                                 float* __restrict__ out,
                                                 int NB, int n, int E) {
    __shared__ float acc[BKT * 2];    // 4 KB
    int b = blockIdx.x;
    int node0 = b << 9;
    int nn = min(BKT, n - node0);
    for (int t = threadIdx.x; t < nn * 2; t += 256)
        acc[t] = h2s[(size_t)node0 * 2 + t];       // init with self term
    __syncthreads();
    int s = (int)base_g[(size_t)b * NBLK];
    int e = (b + 1 < NB) ? (int)base_g[(size_t)(b + 1) * NBLK] : E;
    for (int i = s + threadIdx.x; i < e; i += 256) {
        u64 rec = edge_g[i];
        int r  = (int)((u32)rec & 0x7FFFFu);
        int cl = (int)(((u32)rec >> 19) & 511u);
        float wv = __uint_as_float((u32)(rec >> 32));
        float2 hv = *(const float2*)(h2s + (size_t)r * 2);
        atomicAdd(&acc[cl * 2 + 0], wv * hv.x);
        atomicAdd(&acc[cl * 2 + 1], wv * hv.y);
    }
    __syncthreads();
    float c0 = b2[0], c1 = b2[1];
    for (int j = threadIdx.x; j < nn; j += 256) {
        int node = node0 + j;
        float dv = dinv_g[node];
        float v0 = dv * acc[j * 2 + 0] + c0;
        float v1 = dv * acc[j * 2 + 1] + c1;
        float m = fmaxf(v0, v1);
        float lse = m + logf(expf(v0 - m) + expf(v1 - m));
        float2 ov; ov.x = v0 - lse; ov.y = v1 - lse;
        *(float2*)(out + (size_t)node * 2) = ov;
    }
}

// ---------------- fallback atomic-scatter kernels (R1 proven path) ----------------

__global__ __launch_bounds__(256) void k_init_deg(float* deg, int n) {
    int i = blockIdx.x * blockDim.x + threadIdx.x;
    if (i < n) deg[i] = 1.0f;
}

__global__ __launch_bounds__(256) void k_deg_accum(const int* __restrict__ col,
                                                   const float* __restrict__ w,
                                                   float* __restrict__ deg, int E) {
    int i = blockIdx.x * blockDim.x + threadIdx.x;
    if (i < E) atomicAdd(&deg[col[i]], w[i]);
}

__global__ __launch_bounds__(256) void k_rsqrt(float* deg, int n) {
    int i = blockIdx.x * blockDim.x + threadIdx.x;
    if (i < n) {
        float d = deg[i];
        deg[i] = (d > 0.0f) ? rsqrtf(d) : 0.0f;
    }
}

__global__ __launch_bounds__(256) void k_gemm1_plain(const float* __restrict__ x,
                                                     const float* __restrict__ W1,
                                                     float* __restrict__ h1, int n) {
    __shared__ float sW[176];
    for (int t = threadIdx.x; t < 176; t += blockDim.x) sW[t] = W1[t];
    __syncthreads();
    int i = blockIdx.x * blockDim.x + threadIdx.x;
    if (i >= n) return;
    float xi[11];
#pragma unroll
    for (int k = 0; k < 11; k++) xi[k] = x[(size_t)i * 11 + k];
#pragma unroll
    for (int f = 0; f < 16; f++) {
        float acc = 0.0f;
#pragma unroll
        for (int k = 0; k < 11; k++) acc += xi[k] * sW[k * 16 + f];
        h1[(size_t)i * 16 + f] = acc;
    }
}

__global__ __launch_bounds__(256) void k_scatter16(const int* __restrict__ row,
                                                   const int* __restrict__ col,
                                                   const float* __restrict__ w,
                                                   const float* __restrict__ dinv,
                                                   const float* __restrict__ h1,
                                                   float* __restrict__ acc, int E) {
    int i = blockIdx.x * blockDim.x + threadIdx.x;
    if (i >= E) return;
    int r = row[i], c = col[i];
    float nw = dinv[r] * w[i] * dinv[c];
    const float4* hr = (const float4*)(h1 + (size_t)r * 16);
    float* o = acc + (size_t)c * 16;
#pragma unroll
    for (int q = 0; q < 4; q++) {
        float4 hv = hr[q];
        atomicAdd(o + q * 4 + 0, nw * hv.x);
        atomicAdd(o + q * 4 + 1, nw * hv.y);
        atomicAdd(o + q * 4 + 2, nw * hv.z);
        atomicAdd(o + q * 4 + 3, nw * hv.w);
    }
}

__global__ __launch_bounds__(256) void k_post1(const float* __restrict__ h1,
                                               const float* __restrict__ dinv,
                                               const float* __restrict__ b1,
                                               float* __restrict__ acc, int n) {
    int i = blockIdx.x * blockDim.x + threadIdx.x;
    if (i >= n) return;
    float dv = dinv[i];
    float cs = dv * dv;
#pragma unroll
    for (int f = 0; f < 16; f++) {
        float v = acc[(size_t)i * 16 + f] + cs * h1[(size_t)i * 16 + f] + b1[f];
        acc[(size_t)i * 16 + f] = v > 0.0f ? v : 0.0f;
    }
}

__global__ __launch_bounds__(256) void k_gemm2(const float* __restrict__ hrelu,
                                               const float* __restrict__ W2,
                                               float* __restrict__ h2, int n) {
    __shared__ float sW[32];
    for (int t = threadIdx.x; t < 32; t += blockDim.x) sW[t] = W2[t];
    __syncthreads();
    int i = blockIdx.x * blockDim.x + threadIdx.x;
    if (i >= n) return;
    float a0 = 0.0f, a1 = 0.0f;
#pragma unroll
    for (int f = 0; f < 16; f++) {
        float h = hrelu[(size_t)i * 16 + f];
        a0 += h * sW[f * 2 + 0];
        a1 += h * sW[f * 2 + 1];
    }
    h2[(size_t)i * 2 + 0] = a0;
    h2[(size_t)i * 2 + 1] = a1;
}

__global__ __launch_bounds__(256) void k_scatter2(const int* __restrict__ row,
                                                  const int* __restrict__ col,
                                                  const float* __restrict__ w,
                                                  const float* __restrict__ dinv,
                                                  const float* __restrict__ h2,
                                                  float* __restrict__ out, int E) {
    int i = blockIdx.x * blockDim.x + threadIdx.x;
    if (i >= E) return;
    int r = row[i], c = col[i];
    float nw = dinv[r] * w[i] * dinv[c];
    atomicAdd(&out[(size_t)c * 2 + 0], nw * h2[(size_t)r * 2 + 0]);
    atomicAdd(&out[(size_t)c * 2 + 1], nw * h2[(size_t)r * 2 + 1]);
}

__global__ __launch_bounds__(256) void k_final(const float* __restrict__ h2,
                                               const float* __restrict__ dinv,
                                               const float* __restrict__ b2,
                                               float* __restrict__ out, int n) {
    int i = blockIdx.x * blockDim.x + threadIdx.x;
    if (i >= n) return;
    float dv = dinv[i];
    float cs = dv * dv;
    float v0 = out[(size_t)i * 2 + 0] + cs * h2[(size_t)i * 2 + 0] + b2[0];
    float v1 = out[(size_t)i * 2 + 1] + cs * h2[(size_t)i * 2 + 1] + b2[1];
    float m = fmaxf(v0, v1);
    float lse = m + logf(expf(v0 - m) + expf(v1 - m));
    out[(size_t)i * 2 + 0] = v0 - lse;
    out[(size_t)i * 2 + 1] = v1 - lse;
}

// ---------------- launch ----------------

static inline size_t align64(size_t x) { return (x + 63) & ~(size_t)63; }

extern "C" void kernel_launch(void* const* d_in, const int* in_sizes, int n_in,
                              void* d_out, int out_size, void* d_ws, size_t ws_size,
                              hipStream_t stream) {
    const float* x  = (const float*)d_in[0];
    const int*   ei = (const int*)d_in[1];
    const float* ew = (const float*)d_in[2];
    const float* W1 = (const float*)d_in[3];
    const float* b1 = (const float*)d_in[4];
    const float* W2 = (const float*)d_in[5];
    const float* b2 = (const float*)d_in[6];

    const int n = in_sizes[0] / 11;
    const int E = in_sizes[2];
    const int* rowp = ei;       // sources
    const int* colp = ei + E;   // targets

    const int TB = 256;
    const int gN = (n + TB - 1) / TB;
    const int gE = (E + TB - 1) / TB;

    const int NB = (n + BKT - 1) / BKT;            // buckets
    const int CH = (E + NBLK - 1) / NBLK;          // edges per partition block
    const int M  = NB * NBLK;                      // scan length
    const int SB = (M + 255) / 256;                // scan blocks

    // --- workspace layout (bucketed path) ---
    char* base = (char*)d_ws;
    size_t o_hist = 0;                                        // u32 M
    size_t o_base = align64(o_hist + (size_t)M * 4);          // u32 M
    size_t o_bsum = align64(o_base + (size_t)M * 4);          // u32 SB
    size_t o_dinv = align64(o_bsum + (size_t)SB * 4);         // f32 n
    size_t o_h1   = align64(o_dinv + (size_t)n * 4);          // f32 16n
    size_t o_h2   = align64(o_h1 + (size_t)n * 16 * 4);       // f32 2n
    size_t o_edge = align64(o_h2 + (size_t)n * 2 * 4);        // u64 E
    size_t needed = align64(o_edge + (size_t)E * 8);

    float* outf = (float*)d_out;

    if (ws_size >= needed && n <= (1 << 19) && NB <= NBMAX) {
        u32*   hist_g = (u32*)(base + o_hist);
        u32*   base_g = (u32*)(base + o_base);
        u32*   bsum   = (u32*)(base + o_bsum);
        float* dinv_g = (float*)(base + o_dinv);
        float* h1s    = (float*)(base + o_h1);
        float* h2s    = (float*)(base + o_h2);
        u64*   edge_g = (u64*)(base + o_edge);

        k_count<<<NBLK, TB, 0, stream>>>(colp, hist_g, NB, E, CH);
        k_scan_local32<<<SB, TB, 0, stream>>>(hist_g, base_g, bsum, NB, M);
        k_scan_sums32<<<1, TB, 0, stream>>>(bsum, SB);
        k_scan_add32<<<SB, TB, 0, stream>>>(base_g, bsum, M);
        k_scatter<<<NBLK, TB, 0, stream>>>(rowp, colp, ew, base_g, edge_g, NB, E, CH);
        k_prep<<<NB, TB, 0, stream>>>(edge_g, base_g, x, W1, dinv_g, h1s, NB, n, E);
        k_pull16_b<<<NB, TB, 0, stream>>>(edge_g, base_g, h1s, dinv_g, b1, W2, h2s, NB, n, E);
        k_pull2_b<<<NB, TB, 0, stream>>>(edge_g, base_g, h2s, dinv_g, b2, outf, NB, n, E);
    } else {
        // fallback: atomic-scatter path (R1)
        float* ws   = (float*)d_ws;
        float* dinv = ws;
        float* h1   = ws + (size_t)n;
        float* acc1 = ws + (size_t)n * 17;

        k_init_deg<<<gN, TB, 0, stream>>>(dinv, n);
        k_deg_accum<<<gE, TB, 0, stream>>>(colp, ew, dinv, E);
        k_rsqrt<<<gN, TB, 0, stream>>>(dinv, n);

        k_gemm1_plain<<<gN, TB, 0, stream>>>(x, W1, h1, n);
        hipMemsetAsync(acc1, 0, (size_t)n * 16 * sizeof(float), stream);
        k_scatter16<<<gE, TB, 0, stream>>>(rowp, colp, ew, dinv, h1, acc1, E);
        k_post1<<<gN, TB, 0, stream>>>(h1, dinv, b1, acc1, n);

        float* h2 = h1;
        k_gemm2<<<gN, TB, 0, stream>>>(acc1, W2, h2, n);
        hipMemsetAsync(outf, 0, (size_t)n * 2 * sizeof(float), stream);
        k_scatter2<<<gE, TB, 0, stream>>>(rowp, colp, ew, dinv, h2, outf, E);
        k_final<<<gN, TB, 0, stream>>>(h2, dinv, b2, outf, n);
    }
}